// Round 1
// baseline (495.482 us; speedup 1.0000x reference)
//
#include <hip/hip_runtime.h>
#include <hip/hip_bf16.h>
#include <cstdint>
#include <cstddef>

typedef short bf16x8 __attribute__((ext_vector_type(8)));
typedef float f32x4 __attribute__((ext_vector_type(4)));

#define SEQ 2048
#define NH 16
#define DH 64
#define DM 1024

__device__ __forceinline__ unsigned short f2bf(float f) {
  union { float f; unsigned int u; } v; v.f = f;
  return (unsigned short)((v.u + 0x7FFFu + ((v.u >> 16) & 1u)) >> 16);
}

// ---------------- fp32 -> bf16 convert ----------------
__global__ void __launch_bounds__(256) k_cvt(const float* __restrict__ in,
                                             unsigned short* __restrict__ out, int n) {
  int i = (blockIdx.x * 256 + threadIdx.x) * 4;
  if (i >= n) return;
  float4 v = *(const float4*)(in + i);
  ushort4 o;
  o.x = f2bf(v.x); o.y = f2bf(v.y); o.z = f2bf(v.z); o.w = f2bf(v.w);
  *(ushort4*)(out + i) = o;
}

// ---------------- shared BT-GEMM mainloop: C[128x128] += A[128xK] * Bt[128xK]^T ----
// A row-major [M][1024], Bt row-major [N][1024] (i.e. B transposed). 4 waves,
// each wave owns a 64x64 quadrant as 4x4 MFMA frags (16x16x32 bf16).
__device__ __forceinline__ void gemm_tile_bt(const unsigned short* __restrict__ A,
                                             const unsigned short* __restrict__ Bt,
                                             unsigned short* lA, unsigned short* lB,
                                             int m0, int n0, f32x4 (&acc)[4][4]) {
  const int t = threadIdx.x;
  const int wave = t >> 6, lane = t & 63, quad = lane >> 4, l16 = lane & 15;
  const int mh = (wave >> 1) * 64, nh = (wave & 1) * 64;
  for (int k0 = 0; k0 < DM; k0 += 32) {
    __syncthreads();
#pragma unroll
    for (int r = 0; r < 2; ++r) {
      int e = (r * 256 + t) * 8;           // flat bf16 index in 128x32 tile
      int row = e >> 5, kk = e & 31;
      *(uint4*)(&lA[e]) = *(const uint4*)(&A[(size_t)(m0 + row) * DM + k0 + kk]);
      *(uint4*)(&lB[e]) = *(const uint4*)(&Bt[(size_t)(n0 + row) * DM + k0 + kk]);
    }
    __syncthreads();
    bf16x8 af[4], bfr[4];
#pragma unroll
    for (int i = 0; i < 4; ++i)
      af[i] = *(const bf16x8*)(&lA[(mh + i * 16 + l16) * 32 + quad * 8]);
#pragma unroll
    for (int i = 0; i < 4; ++i)
      bfr[i] = *(const bf16x8*)(&lB[(nh + i * 16 + l16) * 32 + quad * 8]);
#pragma unroll
    for (int mt = 0; mt < 4; ++mt)
#pragma unroll
      for (int nt = 0; nt < 4; ++nt)
        acc[mt][nt] = __builtin_amdgcn_mfma_f32_16x16x32_bf16(af[mt], bfr[nt], acc[mt][nt], 0, 0, 0);
  }
}

// ---------------- GEMM1: qkv = x @ W_in^T + b_in, scatter to Q/K/Vt ----------------
__global__ void __launch_bounds__(256) k_gemm_qkv(
    const unsigned short* __restrict__ X,   // [8192][1024] bf16
    const unsigned short* __restrict__ Wi,  // [3072][1024] bf16 (BT layout)
    const float* __restrict__ bias,         // [3072] fp32
    unsigned short* __restrict__ Qo,        // [4][16][2048][64] (q * log2e/8 folded)
    unsigned short* __restrict__ Ko,        // [4][16][2048][64]
    unsigned short* __restrict__ Vto) {     // [4][16][64][2048]  (V transposed)
  __shared__ unsigned short lA[128 * 32];
  __shared__ unsigned short lB[128 * 32];
  const int t = threadIdx.x;
  const int wave = t >> 6, lane = t & 63, quad = lane >> 4, l16 = lane & 15;
  const int m0 = blockIdx.x * 128, n0 = blockIdx.y * 128;
  f32x4 acc[4][4];
  f32x4 zf = {0.f, 0.f, 0.f, 0.f};
  for (int i = 0; i < 4; ++i)
    for (int j = 0; j < 4; ++j) acc[i][j] = zf;
  gemm_tile_bt(X, Wi, lA, lB, m0, n0, acc);

  const int mh = (wave >> 1) * 64, nh = (wave & 1) * 64;
  const float SCALE = 0.18033688011112042f;  // log2(e) / sqrt(64) -> exp2-domain softmax
#pragma unroll
  for (int nt = 0; nt < 4; ++nt) {
    int gcol = n0 + nh + nt * 16 + l16;       // chunk (q/k/v) is uniform per block
    float bv = bias[gcol];
    if (gcol < 1024) {                        // Q
      int hh = gcol >> 6, dh = gcol & 63;
#pragma unroll
      for (int mt = 0; mt < 4; ++mt) {
        int rowbase = m0 + mh + mt * 16 + quad * 4;
        int bb = rowbase >> 11, sb = rowbase & 2047;
#pragma unroll
        for (int r = 0; r < 4; ++r)
          Qo[((size_t)(bb * NH + hh) * SEQ + sb + r) * DH + dh] =
              f2bf((acc[mt][nt][r] + bv) * SCALE);
      }
    } else if (gcol < 2048) {                 // K
      int c = gcol - 1024; int hh = c >> 6, dh = c & 63;
#pragma unroll
      for (int mt = 0; mt < 4; ++mt) {
        int rowbase = m0 + mh + mt * 16 + quad * 4;
        int bb = rowbase >> 11, sb = rowbase & 2047;
#pragma unroll
        for (int r = 0; r < 4; ++r)
          Ko[((size_t)(bb * NH + hh) * SEQ + sb + r) * DH + dh] = f2bf(acc[mt][nt][r] + bv);
      }
    } else {                                  // V -> transposed, 4 consecutive s packed
      int c = gcol - 2048; int hh = c >> 6, dh = c & 63;
#pragma unroll
      for (int mt = 0; mt < 4; ++mt) {
        int rowbase = m0 + mh + mt * 16 + quad * 4;
        int bb = rowbase >> 11, sb = rowbase & 2047;
        ushort4 pk;
        pk.x = f2bf(acc[mt][nt][0] + bv);
        pk.y = f2bf(acc[mt][nt][1] + bv);
        pk.z = f2bf(acc[mt][nt][2] + bv);
        pk.w = f2bf(acc[mt][nt][3] + bv);
        *(ushort4*)(&Vto[((size_t)(bb * NH + hh) * DH + dh) * SEQ + sb]) = pk;
      }
    }
  }
}

// ---------------- flash attention: 64 q-rows per block, online softmax ----------------
__global__ void __launch_bounds__(256) k_attn(
    const unsigned short* __restrict__ Q,   // [b][h][s][64], scale folded
    const unsigned short* __restrict__ K,   // [b][h][s][64]
    const unsigned short* __restrict__ Vt,  // [b][h][64][s]
    unsigned short* __restrict__ Ao,        // [b][s][1024] bf16
    const int* __restrict__ causal_p) {
  __shared__ unsigned short lK[64 * 64];
  __shared__ unsigned short lV[64 * 64];
  __shared__ unsigned short lP[4 * 16 * 80];  // per-wave P tile, stride 80 to break banks

  const int t = threadIdx.x;
  const int wave = t >> 6, lane = t & 63, quad = lane >> 4, l16 = lane & 15;
  const int qt = blockIdx.x, h = blockIdx.y, b = blockIdx.z;
  const int bh = b * NH + h;
  const int q0 = qt * 64;
  const int causal = causal_p[0];

  const unsigned short* Qb = Q + (size_t)bh * SEQ * DH;
  const unsigned short* Kb = K + (size_t)bh * SEQ * DH;
  const unsigned short* Vb = Vt + (size_t)bh * DH * SEQ;

  // Q fragments live in registers the whole kernel (A-layout: m=l16, k=quad*8+j)
  const int qrow = q0 + wave * 16 + l16;
  bf16x8 qf0 = *(const bf16x8*)(&Qb[qrow * DH + quad * 8]);
  bf16x8 qf1 = *(const bf16x8*)(&Qb[qrow * DH + 32 + quad * 8]);

  f32x4 oacc[4];
  f32x4 zf = {0.f, 0.f, 0.f, 0.f};
  for (int i = 0; i < 4; ++i) oacc[i] = zf;
  float m_run[4], l_run[4];
  for (int r = 0; r < 4; ++r) { m_run[r] = -1e30f; l_run[r] = 0.f; }

  unsigned short* lPw = lP + wave * 16 * 80;
  const int ktmax = causal ? qt : (SEQ / 64 - 1);

  for (int kt = 0; kt <= ktmax; ++kt) {
    const int k0 = kt * 64;
    __syncthreads();  // prior iteration's PV reads done before restaging
#pragma unroll
    for (int r = 0; r < 2; ++r) {
      int e = (r * 256 + t) * 8;
      int row = e >> 6, col = e & 63;
      *(uint4*)(&lK[e]) = *(const uint4*)(&Kb[(k0 + row) * DH + col]);
      *(uint4*)(&lV[e]) = *(const uint4*)(&Vb[row * SEQ + k0 + col]);
    }
    __syncthreads();

    // S = Q Kt : wave's 16 q-rows x 64 k-cols
    f32x4 s[4];
#pragma unroll
    for (int nt = 0; nt < 4; ++nt) {
      s[nt] = zf;
      bf16x8 kf0 = *(const bf16x8*)(&lK[(nt * 16 + l16) * 64 + quad * 8]);
      bf16x8 kf1 = *(const bf16x8*)(&lK[(nt * 16 + l16) * 64 + 32 + quad * 8]);
      s[nt] = __builtin_amdgcn_mfma_f32_16x16x32_bf16(qf0, kf0, s[nt], 0, 0, 0);
      s[nt] = __builtin_amdgcn_mfma_f32_16x16x32_bf16(qf1, kf1, s[nt], 0, 0, 0);
    }

    if (causal && kt == qt) {  // diagonal tile only
#pragma unroll
      for (int nt = 0; nt < 4; ++nt) {
        int kcol = k0 + nt * 16 + l16;
#pragma unroll
        for (int r = 0; r < 4; ++r) {
          int qg = q0 + wave * 16 + quad * 4 + r;
          if (kcol > qg) s[nt][r] = -1e30f;
        }
      }
    }

    // online softmax (exp2 domain); row r lives in this quad's 16 lanes
#pragma unroll
    for (int r = 0; r < 4; ++r) {
      float mx = fmaxf(fmaxf(s[0][r], s[1][r]), fmaxf(s[2][r], s[3][r]));
      mx = fmaxf(mx, __shfl_xor(mx, 1));
      mx = fmaxf(mx, __shfl_xor(mx, 2));
      mx = fmaxf(mx, __shfl_xor(mx, 4));
      mx = fmaxf(mx, __shfl_xor(mx, 8));
      float mnew = fmaxf(m_run[r], mx);
      float alpha = exp2f(m_run[r] - mnew);
      m_run[r] = mnew;
      float rs = 0.f;
#pragma unroll
      for (int nt = 0; nt < 4; ++nt) {
        float p = exp2f(s[nt][r] - mnew);
        rs += p;
        lPw[(quad * 4 + r) * 80 + nt * 16 + l16] = f2bf(p);  // C-layout -> LDS
      }
      rs += __shfl_xor(rs, 1);
      rs += __shfl_xor(rs, 2);
      rs += __shfl_xor(rs, 4);
      rs += __shfl_xor(rs, 8);
      l_run[r] = l_run[r] * alpha + rs;
#pragma unroll
      for (int nt = 0; nt < 4; ++nt) oacc[nt][r] *= alpha;
    }

    // wave-local: make this wave's P writes visible to its own ds_reads
    asm volatile("s_waitcnt lgkmcnt(0)" ::: "memory");

    // P back out of LDS in A-operand layout
    bf16x8 pf0 = *(const bf16x8*)(&lPw[l16 * 80 + quad * 8]);
    bf16x8 pf1 = *(const bf16x8*)(&lPw[l16 * 80 + 32 + quad * 8]);
#pragma unroll
    for (int nt = 0; nt < 4; ++nt) {
      bf16x8 vf0 = *(const bf16x8*)(&lV[(nt * 16 + l16) * 64 + quad * 8]);
      bf16x8 vf1 = *(const bf16x8*)(&lV[(nt * 16 + l16) * 64 + 32 + quad * 8]);
      oacc[nt] = __builtin_amdgcn_mfma_f32_16x16x32_bf16(pf0, vf0, oacc[nt], 0, 0, 0);
      oacc[nt] = __builtin_amdgcn_mfma_f32_16x16x32_bf16(pf1, vf1, oacc[nt], 0, 0, 0);
    }
  }

  // epilogue: O /= l, write [b][s][h*64+dh]
#pragma unroll
  for (int nt = 0; nt < 4; ++nt) {
    int dh = nt * 16 + l16;
#pragma unroll
    for (int r = 0; r < 4; ++r) {
      int qg = q0 + wave * 16 + quad * 4 + r;
      Ao[(size_t)(b * SEQ + qg) * DM + h * DH + dh] = f2bf(oacc[nt][r] / l_run[r]);
    }
  }
}

// ---------------- GEMM3: out = attn_out @ W_out^T + b_out ----------------
__global__ void __launch_bounds__(256) k_gemm_out(
    const unsigned short* __restrict__ Ai,  // [8192][1024] bf16
    const unsigned short* __restrict__ Wo,  // [1024][1024] bf16 (BT)
    const float* __restrict__ bias,         // [1024]
    float* __restrict__ C) {                // [8192][1024] fp32
  __shared__ unsigned short lA[128 * 32];
  __shared__ unsigned short lB[128 * 32];
  const int t = threadIdx.x;
  const int wave = t >> 6, lane = t & 63, quad = lane >> 4, l16 = lane & 15;
  const int m0 = blockIdx.x * 128, n0 = blockIdx.y * 128;
  f32x4 acc[4][4];
  f32x4 zf = {0.f, 0.f, 0.f, 0.f};
  for (int i = 0; i < 4; ++i)
    for (int j = 0; j < 4; ++j) acc[i][j] = zf;
  gemm_tile_bt(Ai, Wo, lA, lB, m0, n0, acc);
  const int mh = (wave >> 1) * 64, nh = (wave & 1) * 64;
#pragma unroll
  for (int nt = 0; nt < 4; ++nt) {
    int gcol = n0 + nh + nt * 16 + l16;
    float bv = bias[gcol];
#pragma unroll
    for (int mt = 0; mt < 4; ++mt) {
      int rowbase = m0 + mh + mt * 16 + quad * 4;
#pragma unroll
      for (int r = 0; r < 4; ++r)
        C[(size_t)(rowbase + r) * DM + gcol] = acc[mt][nt][r] + bv;
    }
  }
}

extern "C" void kernel_launch(void* const* d_in, const int* in_sizes, int n_in,
                              void* d_out, int out_size, void* d_ws, size_t ws_size,
                              hipStream_t stream) {
  (void)in_sizes; (void)n_in; (void)out_size; (void)ws_size;
  const float* x     = (const float*)d_in[0];
  const float* W_in  = (const float*)d_in[1];
  const float* b_in  = (const float*)d_in[2];
  const float* W_out = (const float*)d_in[3];
  const float* b_out = (const float*)d_in[4];
  const int* causal  = (const int*)d_in[5];
  float* out = (float*)d_out;
  char* ws = (char*)d_ws;

  // workspace layout (72 MB total); Aob aliases xb (xb dead after gemm_qkv)
  unsigned short* xb  = (unsigned short*)(ws + 0);                    // 16 MB
  unsigned short* Aob = (unsigned short*)(ws + 0);                    // 16 MB (alias)
  unsigned short* Wib = (unsigned short*)(ws + (size_t)(16 << 20));   //  6 MB
  unsigned short* Wob = (unsigned short*)(ws + (size_t)(22 << 20));   //  2 MB
  unsigned short* Qb  = (unsigned short*)(ws + (size_t)(24 << 20));   // 16 MB
  unsigned short* Kb  = (unsigned short*)(ws + (size_t)(40 << 20));   // 16 MB
  unsigned short* Vtb = (unsigned short*)(ws + (size_t)(56 << 20));   // 16 MB

  k_cvt<<<8192, 256, 0, stream>>>(x, xb, 8 * 1024 * 1024);
  k_cvt<<<3072, 256, 0, stream>>>(W_in, Wib, 3 * 1024 * 1024);
  k_cvt<<<1024, 256, 0, stream>>>(W_out, Wob, 1024 * 1024);
  k_gemm_qkv<<<dim3(64, 24), 256, 0, stream>>>(xb, Wib, b_in, Qb, Kb, Vtb);
  k_attn<<<dim3(32, 16, 4), 256, 0, stream>>>(Qb, Kb, Vtb, Aob, causal);
  k_gemm_out<<<dim3(64, 8), 256, 0, stream>>>(Aob, Wob, b_out, out);
}

// Round 2
// 413.452 us; speedup vs baseline: 1.1984x; 1.1984x over previous
//
#include <hip/hip_runtime.h>
#include <hip/hip_bf16.h>
#include <cstdint>
#include <cstddef>

typedef short bf16x8 __attribute__((ext_vector_type(8)));
typedef float f32x4 __attribute__((ext_vector_type(4)));

#define SEQ 2048
#define NH 16
#define DH 64
#define DM 1024

__device__ __forceinline__ unsigned short f2bf(float f) {
  union { float f; unsigned int u; } v; v.f = f;
  return (unsigned short)((v.u + 0x7FFFu + ((v.u >> 16) & 1u)) >> 16);
}

// ---------------- fp32 -> bf16 convert ----------------
__global__ void __launch_bounds__(256) k_cvt(const float* __restrict__ in,
                                             unsigned short* __restrict__ out, int n) {
  int i = (blockIdx.x * 256 + threadIdx.x) * 4;
  if (i >= n) return;
  float4 v = *(const float4*)(in + i);
  ushort4 o;
  o.x = f2bf(v.x); o.y = f2bf(v.y); o.z = f2bf(v.z); o.w = f2bf(v.w);
  *(ushort4*)(out + i) = o;
}

// ---------------- shared BT-GEMM mainloop: C[128x128] += A[128xK] * Bt[128xK]^T ----
// LDS tiles padded to stride 40 shorts (80 B) -> frag-read bank stride 20 -> 2-way (free).
#define GSTR 40
__device__ __forceinline__ void gemm_tile_bt(const unsigned short* __restrict__ A,
                                             const unsigned short* __restrict__ Bt,
                                             unsigned short* lA, unsigned short* lB,
                                             int m0, int n0, f32x4 (&acc)[4][4]) {
  const int t = threadIdx.x;
  const int wave = t >> 6, lane = t & 63, quad = lane >> 4, l16 = lane & 15;
  const int mh = (wave >> 1) * 64, nh = (wave & 1) * 64;
  for (int k0 = 0; k0 < DM; k0 += 32) {
    __syncthreads();
#pragma unroll
    for (int r = 0; r < 2; ++r) {
      int e = (r * 256 + t) * 8;           // flat bf16 index in 128x32 tile
      int row = e >> 5, kk = e & 31;
      *(uint4*)(&lA[row * GSTR + kk]) = *(const uint4*)(&A[(size_t)(m0 + row) * DM + k0 + kk]);
      *(uint4*)(&lB[row * GSTR + kk]) = *(const uint4*)(&Bt[(size_t)(n0 + row) * DM + k0 + kk]);
    }
    __syncthreads();
    bf16x8 af[4], bfr[4];
#pragma unroll
    for (int i = 0; i < 4; ++i)
      af[i] = *(const bf16x8*)(&lA[(mh + i * 16 + l16) * GSTR + quad * 8]);
#pragma unroll
    for (int i = 0; i < 4; ++i)
      bfr[i] = *(const bf16x8*)(&lB[(nh + i * 16 + l16) * GSTR + quad * 8]);
#pragma unroll
    for (int mt = 0; mt < 4; ++mt)
#pragma unroll
      for (int nt = 0; nt < 4; ++nt)
        acc[mt][nt] = __builtin_amdgcn_mfma_f32_16x16x32_bf16(af[mt], bfr[nt], acc[mt][nt], 0, 0, 0);
  }
}

// ---------------- GEMM1: qkv = x @ W_in^T + b_in, scatter to Q/K/Vt ----------------
__global__ void __launch_bounds__(256) k_gemm_qkv(
    const unsigned short* __restrict__ X,   // [8192][1024] bf16
    const unsigned short* __restrict__ Wi,  // [3072][1024] bf16 (BT layout)
    const float* __restrict__ bias,         // [3072] fp32
    unsigned short* __restrict__ Qo,        // [4][16][2048][64] (q * log2e/8 folded)
    unsigned short* __restrict__ Ko,        // [4][16][2048][64]
    unsigned short* __restrict__ Vto) {     // [4][16][64][2048]  (V transposed)
  __shared__ unsigned short lA[128 * GSTR];
  __shared__ unsigned short lB[128 * GSTR];
  const int t = threadIdx.x;
  const int wave = t >> 6, lane = t & 63, quad = lane >> 4, l16 = lane & 15;
  const int m0 = blockIdx.x * 128, n0 = blockIdx.y * 128;
  f32x4 acc[4][4];
  f32x4 zf = {0.f, 0.f, 0.f, 0.f};
  for (int i = 0; i < 4; ++i)
    for (int j = 0; j < 4; ++j) acc[i][j] = zf;
  gemm_tile_bt(X, Wi, lA, lB, m0, n0, acc);

  const int mh = (wave >> 1) * 64, nh = (wave & 1) * 64;
  const float SCALE = 0.18033688011112042f;  // log2(e) / sqrt(64) -> exp2-domain softmax
#pragma unroll
  for (int nt = 0; nt < 4; ++nt) {
    int gcol = n0 + nh + nt * 16 + l16;       // chunk (q/k/v) is uniform per block
    float bv = bias[gcol];
    if (gcol < 1024) {                        // Q
      int hh = gcol >> 6, dh = gcol & 63;
#pragma unroll
      for (int mt = 0; mt < 4; ++mt) {
        int rowbase = m0 + mh + mt * 16 + quad * 4;
        int bb = rowbase >> 11, sb = rowbase & 2047;
#pragma unroll
        for (int r = 0; r < 4; ++r)
          Qo[((size_t)(bb * NH + hh) * SEQ + sb + r) * DH + dh] =
              f2bf((acc[mt][nt][r] + bv) * SCALE);
      }
    } else if (gcol < 2048) {                 // K
      int c = gcol - 1024; int hh = c >> 6, dh = c & 63;
#pragma unroll
      for (int mt = 0; mt < 4; ++mt) {
        int rowbase = m0 + mh + mt * 16 + quad * 4;
        int bb = rowbase >> 11, sb = rowbase & 2047;
#pragma unroll
        for (int r = 0; r < 4; ++r)
          Ko[((size_t)(bb * NH + hh) * SEQ + sb + r) * DH + dh] = f2bf(acc[mt][nt][r] + bv);
      }
    } else {                                  // V -> transposed, 4 consecutive s packed
      int c = gcol - 2048; int hh = c >> 6, dh = c & 63;
#pragma unroll
      for (int mt = 0; mt < 4; ++mt) {
        int rowbase = m0 + mh + mt * 16 + quad * 4;
        int bb = rowbase >> 11, sb = rowbase & 2047;
        ushort4 pk;
        pk.x = f2bf(acc[mt][nt][0] + bv);
        pk.y = f2bf(acc[mt][nt][1] + bv);
        pk.z = f2bf(acc[mt][nt][2] + bv);
        pk.w = f2bf(acc[mt][nt][3] + bv);
        *(ushort4*)(&Vto[((size_t)(bb * NH + hh) * DH + dh) * SEQ + sb]) = pk;
      }
    }
  }
}

// ---------------- flash attention ----------------
// Paired q-tiles (qtA = x, qtB = 31-x) share K/V staging: uniform MFMA work per
// block (33 tile-halves causal), 1024 blocks == 4/CU all-resident.
// LDS rows padded to 72 shorts -> 2-way bank access (free).
#define ASTR 72

__device__ __forceinline__ void softmax_update(f32x4 (&s)[4], float (&m_run)[4],
                                               float (&l_run)[4], f32x4 (&oacc)[4],
                                               unsigned short* lPw, int quad, int l16) {
#pragma unroll
  for (int r = 0; r < 4; ++r) {
    float mx = fmaxf(fmaxf(s[0][r], s[1][r]), fmaxf(s[2][r], s[3][r]));
    mx = fmaxf(mx, __shfl_xor(mx, 1));
    mx = fmaxf(mx, __shfl_xor(mx, 2));
    mx = fmaxf(mx, __shfl_xor(mx, 4));
    mx = fmaxf(mx, __shfl_xor(mx, 8));
    float mnew = fmaxf(m_run[r], mx);
    float alpha = __builtin_amdgcn_exp2f(m_run[r] - mnew);
    m_run[r] = mnew;
    float rs = 0.f;
#pragma unroll
    for (int nt = 0; nt < 4; ++nt) {
      float p = __builtin_amdgcn_exp2f(s[nt][r] - mnew);
      rs += p;
      lPw[(quad * 4 + r) * ASTR + nt * 16 + l16] = f2bf(p);
    }
    rs += __shfl_xor(rs, 1);
    rs += __shfl_xor(rs, 2);
    rs += __shfl_xor(rs, 4);
    rs += __shfl_xor(rs, 8);
    l_run[r] = l_run[r] * alpha + rs;
#pragma unroll
    for (int nt = 0; nt < 4; ++nt) oacc[nt][r] *= alpha;
  }
}

__global__ void __launch_bounds__(256, 4) k_attn(
    const unsigned short* __restrict__ Q,   // [b][h][s][64], scale folded
    const unsigned short* __restrict__ K,   // [b][h][s][64]
    const unsigned short* __restrict__ Vt,  // [b][h][64][s]
    unsigned short* __restrict__ Ao,        // [b][s][1024] bf16
    const int* __restrict__ causal_p) {
  __shared__ unsigned short lK[64 * ASTR];
  __shared__ unsigned short lV[64 * ASTR];
  __shared__ unsigned short lPA[4 * 16 * ASTR];
  __shared__ unsigned short lPB[4 * 16 * ASTR];

  const int t = threadIdx.x;
  const int wave = t >> 6, lane = t & 63, quad = lane >> 4, l16 = lane & 15;
  const int x = blockIdx.x, h = blockIdx.y, b = blockIdx.z;
  const int qtA = x, qtB = 31 - x;
  const int bh = b * NH + h;
  const int causal = causal_p[0];
  const int ktA = causal ? qtA : 31;
  const int ktB = causal ? qtB : 31;
  const int q0A = qtA * 64, q0B = qtB * 64;

  const unsigned short* Qb = Q + (size_t)bh * SEQ * DH;
  const unsigned short* Kb = K + (size_t)bh * SEQ * DH;
  const unsigned short* Vb = Vt + (size_t)bh * DH * SEQ;

  // Q fragments in registers for both tiles (A-layout: m=l16, k=quad*8+j)
  bf16x8 qA0 = *(const bf16x8*)(&Qb[(q0A + wave * 16 + l16) * DH + quad * 8]);
  bf16x8 qA1 = *(const bf16x8*)(&Qb[(q0A + wave * 16 + l16) * DH + 32 + quad * 8]);
  bf16x8 qB0 = *(const bf16x8*)(&Qb[(q0B + wave * 16 + l16) * DH + quad * 8]);
  bf16x8 qB1 = *(const bf16x8*)(&Qb[(q0B + wave * 16 + l16) * DH + 32 + quad * 8]);

  f32x4 zf = {0.f, 0.f, 0.f, 0.f};
  f32x4 oA[4], oB[4];
  for (int i = 0; i < 4; ++i) { oA[i] = zf; oB[i] = zf; }
  float mA[4], lAr[4], mB[4], lBr[4];
  for (int r = 0; r < 4; ++r) { mA[r] = -1e30f; lAr[r] = 0.f; mB[r] = -1e30f; lBr[r] = 0.f; }

  unsigned short* lPa = lPA + wave * 16 * ASTR;
  unsigned short* lPb = lPB + wave * 16 * ASTR;

  // staging: thread t handles 16 contiguous elems of the 64x64 tile
  const int row_s = t >> 2, col_s = (t & 3) * 16;
  const unsigned short* gK = Kb + row_s * DH + col_s;       // K[s][d]
  const unsigned short* gV = Vb + row_s * SEQ + col_s;      // Vt[d][s]
  uint4 pk0 = *(const uint4*)(gK);
  uint4 pk1 = *(const uint4*)(gK + 8);
  uint4 pv0 = *(const uint4*)(gV);
  uint4 pv1 = *(const uint4*)(gV + 8);

  for (int kt = 0; kt <= ktB; ++kt) {
    __syncthreads();  // prior iteration's LDS reads done
    *(uint4*)(&lK[row_s * ASTR + col_s]) = pk0;
    *(uint4*)(&lK[row_s * ASTR + col_s + 8]) = pk1;
    *(uint4*)(&lV[row_s * ASTR + col_s]) = pv0;
    *(uint4*)(&lV[row_s * ASTR + col_s + 8]) = pv1;
    __syncthreads();
    if (kt < ktB) {  // prefetch next K/V tile into regs during compute
      const unsigned short* nK = gK + (size_t)(kt + 1) * 64 * DH;
      const unsigned short* nV = gV + (kt + 1) * 64;
      pk0 = *(const uint4*)(nK);
      pk1 = *(const uint4*)(nK + 8);
      pv0 = *(const uint4*)(nV);
      pv1 = *(const uint4*)(nV + 8);
    }
    const bool doA = (kt <= ktA);
    const int k0 = kt * 64;

    f32x4 sB[4], sA[4];
#pragma unroll
    for (int nt = 0; nt < 4; ++nt) {
      bf16x8 kf0 = *(const bf16x8*)(&lK[(nt * 16 + l16) * ASTR + quad * 8]);
      bf16x8 kf1 = *(const bf16x8*)(&lK[(nt * 16 + l16) * ASTR + 32 + quad * 8]);
      f32x4 zb = zf;
      zb = __builtin_amdgcn_mfma_f32_16x16x32_bf16(qB0, kf0, zb, 0, 0, 0);
      zb = __builtin_amdgcn_mfma_f32_16x16x32_bf16(qB1, kf1, zb, 0, 0, 0);
      sB[nt] = zb;
      if (doA) {
        f32x4 za = zf;
        za = __builtin_amdgcn_mfma_f32_16x16x32_bf16(qA0, kf0, za, 0, 0, 0);
        za = __builtin_amdgcn_mfma_f32_16x16x32_bf16(qA1, kf1, za, 0, 0, 0);
        sA[nt] = za;
      }
    }

    if (causal && kt == qtB) {
#pragma unroll
      for (int nt = 0; nt < 4; ++nt) {
        int kcol = k0 + nt * 16 + l16;
#pragma unroll
        for (int r = 0; r < 4; ++r) {
          int qg = q0B + wave * 16 + quad * 4 + r;
          if (kcol > qg) sB[nt][r] = -1e30f;
        }
      }
    }
    if (causal && doA && kt == qtA) {
#pragma unroll
      for (int nt = 0; nt < 4; ++nt) {
        int kcol = k0 + nt * 16 + l16;
#pragma unroll
        for (int r = 0; r < 4; ++r) {
          int qg = q0A + wave * 16 + quad * 4 + r;
          if (kcol > qg) sA[nt][r] = -1e30f;
        }
      }
    }

    softmax_update(sB, mB, lBr, oB, lPb, quad, l16);
    if (doA) softmax_update(sA, mA, lAr, oA, lPa, quad, l16);

    // wave-local: make this wave's P writes visible to its own ds_reads
    asm volatile("s_waitcnt lgkmcnt(0)" ::: "memory");

    bf16x8 pB0 = *(const bf16x8*)(&lPb[l16 * ASTR + quad * 8]);
    bf16x8 pB1 = *(const bf16x8*)(&lPb[l16 * ASTR + 32 + quad * 8]);
    bf16x8 pA0 = pB0, pA1 = pB1;
    if (doA) {
      pA0 = *(const bf16x8*)(&lPa[l16 * ASTR + quad * 8]);
      pA1 = *(const bf16x8*)(&lPa[l16 * ASTR + 32 + quad * 8]);
    }
#pragma unroll
    for (int nt = 0; nt < 4; ++nt) {
      bf16x8 vf0 = *(const bf16x8*)(&lV[(nt * 16 + l16) * ASTR + quad * 8]);
      bf16x8 vf1 = *(const bf16x8*)(&lV[(nt * 16 + l16) * ASTR + 32 + quad * 8]);
      oB[nt] = __builtin_amdgcn_mfma_f32_16x16x32_bf16(pB0, vf0, oB[nt], 0, 0, 0);
      oB[nt] = __builtin_amdgcn_mfma_f32_16x16x32_bf16(pB1, vf1, oB[nt], 0, 0, 0);
      if (doA) {
        oA[nt] = __builtin_amdgcn_mfma_f32_16x16x32_bf16(pA0, vf0, oA[nt], 0, 0, 0);
        oA[nt] = __builtin_amdgcn_mfma_f32_16x16x32_bf16(pA1, vf1, oA[nt], 0, 0, 0);
      }
    }
  }

  // epilogue: O /= l, write [b][s][h*64+dh] for both tiles
#pragma unroll
  for (int nt = 0; nt < 4; ++nt) {
    int dh = nt * 16 + l16;
#pragma unroll
    for (int r = 0; r < 4; ++r) {
      int qgB = q0B + wave * 16 + quad * 4 + r;
      Ao[(size_t)(b * SEQ + qgB) * DM + h * DH + dh] = f2bf(oB[nt][r] / lBr[r]);
      int qgA = q0A + wave * 16 + quad * 4 + r;
      Ao[(size_t)(b * SEQ + qgA) * DM + h * DH + dh] = f2bf(oA[nt][r] / lAr[r]);
    }
  }
}

// ---------------- GEMM3: out = attn_out @ W_out^T + b_out ----------------
__global__ void __launch_bounds__(256) k_gemm_out(
    const unsigned short* __restrict__ Ai,  // [8192][1024] bf16
    const unsigned short* __restrict__ Wo,  // [1024][1024] bf16 (BT)
    const float* __restrict__ bias,         // [1024]
    float* __restrict__ C) {                // [8192][1024] fp32
  __shared__ unsigned short lA[128 * GSTR];
  __shared__ unsigned short lB[128 * GSTR];
  const int t = threadIdx.x;
  const int wave = t >> 6, lane = t & 63, quad = lane >> 4, l16 = lane & 15;
  const int m0 = blockIdx.x * 128, n0 = blockIdx.y * 128;
  f32x4 acc[4][4];
  f32x4 zf = {0.f, 0.f, 0.f, 0.f};
  for (int i = 0; i < 4; ++i)
    for (int j = 0; j < 4; ++j) acc[i][j] = zf;
  gemm_tile_bt(Ai, Wo, lA, lB, m0, n0, acc);
  const int mh = (wave >> 1) * 64, nh = (wave & 1) * 64;
#pragma unroll
  for (int nt = 0; nt < 4; ++nt) {
    int gcol = n0 + nh + nt * 16 + l16;
    float bv = bias[gcol];
#pragma unroll
    for (int mt = 0; mt < 4; ++mt) {
      int rowbase = m0 + mh + mt * 16 + quad * 4;
#pragma unroll
      for (int r = 0; r < 4; ++r)
        C[(size_t)(rowbase + r) * DM + gcol] = acc[mt][nt][r] + bv;
    }
  }
}

extern "C" void kernel_launch(void* const* d_in, const int* in_sizes, int n_in,
                              void* d_out, int out_size, void* d_ws, size_t ws_size,
                              hipStream_t stream) {
  (void)in_sizes; (void)n_in; (void)out_size; (void)ws_size;
  const float* x     = (const float*)d_in[0];
  const float* W_in  = (const float*)d_in[1];
  const float* b_in  = (const float*)d_in[2];
  const float* W_out = (const float*)d_in[3];
  const float* b_out = (const float*)d_in[4];
  const int* causal  = (const int*)d_in[5];
  float* out = (float*)d_out;
  char* ws = (char*)d_ws;

  // workspace layout (72 MB total); Aob aliases xb (xb dead after gemm_qkv)
  unsigned short* xb  = (unsigned short*)(ws + 0);                    // 16 MB
  unsigned short* Aob = (unsigned short*)(ws + 0);                    // 16 MB (alias)
  unsigned short* Wib = (unsigned short*)(ws + (size_t)(16 << 20));   //  6 MB
  unsigned short* Wob = (unsigned short*)(ws + (size_t)(22 << 20));   //  2 MB
  unsigned short* Qb  = (unsigned short*)(ws + (size_t)(24 << 20));   // 16 MB
  unsigned short* Kb  = (unsigned short*)(ws + (size_t)(40 << 20));   // 16 MB
  unsigned short* Vtb = (unsigned short*)(ws + (size_t)(56 << 20));   // 16 MB

  k_cvt<<<8192, 256, 0, stream>>>(x, xb, 8 * 1024 * 1024);
  k_cvt<<<3072, 256, 0, stream>>>(W_in, Wib, 3 * 1024 * 1024);
  k_cvt<<<1024, 256, 0, stream>>>(W_out, Wob, 1024 * 1024);
  k_gemm_qkv<<<dim3(64, 24), 256, 0, stream>>>(xb, Wib, b_in, Qb, Kb, Vtb);
  k_attn<<<dim3(16, 16, 4), 256, 0, stream>>>(Qb, Kb, Vtb, Aob, causal);
  k_gemm_out<<<dim3(64, 8), 256, 0, stream>>>(Aob, Wob, b_out, out);
}